// Round 7
// baseline (1869.719 us; speedup 1.0000x reference)
//
#include <hip/hip_runtime.h>
#include <hip/hip_bf16.h>

#define IDIM 80
#define HDIM 512
#define ODIM 128
#define G5   5
#define BB   512
#define TT   512
#define PDIM 1285          // G*2*ODIM + G
#define GDIM 1536          // 3*HDIM
#define NW   16            // worker blocks
#define NLAUNCH 128        // workers = blockIdx%8==0 -> same XCD if round-robin
#define JPB  32            // h-elements per worker

// xp[b,g] = dot(ys[b,T-1,:], W_ih[g,:]) + b_ih[g]
__global__ void __launch_bounds__(512) xp_kernel(
    const float* __restrict__ ys, const float* __restrict__ W_ih,
    const float* __restrict__ b_ih, float* __restrict__ xp)
{
  __shared__ float wih[32 * 82];
  __shared__ float bihs[32];
  const int tid = threadIdx.x;
  const int g0 = blockIdx.x * 32;
  const int b0 = blockIdx.y * 64;
  for (int idx = tid; idx < 32 * IDIM; idx += 512) {
    int g = idx / IDIM, f = idx % IDIM;
    wih[g * 82 + f] = W_ih[(size_t)(g0 + g) * IDIM + f];
  }
  if (tid < 32) bihs[tid] = b_ih[g0 + tid];
  __syncthreads();
  const int g = tid & 31, bo = tid >> 5;
  for (int pass = 0; pass < 4; ++pass) {
    int b = b0 + pass * 16 + bo;
    const float* yrow = ys + ((size_t)b * TT + (TT - 1)) * IDIM;
    float acc = bihs[g];
    #pragma unroll
    for (int f = 0; f < IDIM; f += 2) {
      float2 wv = *(const float2*)(&wih[g * 82 + f]);
      float2 yv = *(const float2*)(&yrow[f]);
      acc += wv.x * yv.x + wv.y * yv.y;
    }
    xp[(size_t)b * GDIM + g0 + g] = acc;
  }
}

// FAST=1: exchange through the local XCD L2 — plain (workgroup-scope) store,
//   CAS-poll with never-matching expected (genuine RMW at the L2 atomic unit:
//   cannot be folded to a cached load, cannot be stale-served by L1).
//   Mirror AGENT store + guarded AGENT fallback poll keeps it correct even if
//   the L2 model is wrong.
// FAST=0: round-6-proven AGENT store + AGENT load poll at IF.
template<int FAST>
__device__ __forceinline__ void run_steps(
    int tid, int c, int jglob, bool prod,
    const float4 (&wreg)[3][8], const float (&bias)[3],
    const float* __restrict__ xp,
    unsigned long long* __restrict__ hw, unsigned long long* __restrict__ mir,
    float* __restrict__ last, float (*hs)[16 * 36])
{
  const int j = tid;
  const int jphys = (j >> 5) * 36 + (j & 31);
  const int pphys = (jglob >> 5) * 36 + (jglob & 31);

  for (int b = 0; b < BB; ++b) {
    float xr = 0.f, xz = 0.f, xn = 0.f;
    if (prod) {
      const float* xpb = xp + (size_t)b * GDIM;  // plain cached (proven)
      xr = xpb[jglob];
      xz = xpb[512 + jglob];
      xn = xpb[1024 + jglob];
    }

    const float* hbase = &hs[b & 1][c * 36];
    float4 h4[8];
    #pragma unroll
    for (int i = 0; i < 8; ++i) h4[i] = ((const float4*)hbase)[i];

    float gsum[3];
    #pragma unroll
    for (int g = 0; g < 3; ++g) {
      float a0 = 0.f, a1 = 0.f, a2 = 0.f, a3 = 0.f;
      #pragma unroll
      for (int i = 0; i < 8; ++i) {
        a0 += wreg[g][i].x * h4[i].x; a1 += wreg[g][i].y * h4[i].y;
        a2 += wreg[g][i].z * h4[i].z; a3 += wreg[g][i].w * h4[i].w;
      }
      float acc = (a0 + a1) + (a2 + a3);
      acc += __shfl_xor(acc, 1);
      acc += __shfl_xor(acc, 2);
      acc += __shfl_xor(acc, 4);
      acc += __shfl_xor(acc, 8);
      gsum[g] = acc;
    }

    unsigned long long* slot  = hw  + (size_t)(b & 1) * HDIM;
    unsigned long long* mslot = mir + (size_t)(b & 1) * HDIM;

    if (prod) {
      float h_old = hs[b & 1][pphys];
      float r = 1.f / (1.f + __expf(-(xr + gsum[0] + bias[0])));
      float z = 1.f / (1.f + __expf(-(xz + gsum[1] + bias[1])));
      float e2 = __expf(2.f * (xn + r * (gsum[2] + bias[2])));
      float n = 1.f - 2.f / (e2 + 1.f);          // tanh, overflow-safe
      float hnew = (1.f - z) * n + z * h_old;
      union { float f; unsigned u; } cv; cv.f = hnew;
      unsigned long long pv = ((unsigned long long)(unsigned)b << 32) | cv.u;
      if constexpr (FAST != 0) {
        __hip_atomic_store(&slot[jglob], pv, __ATOMIC_RELAXED,
                           __HIP_MEMORY_SCOPE_WORKGROUP);   // local L2 (write-through L1)
        __hip_atomic_store(&mslot[jglob], pv, __ATOMIC_RELAXED,
                           __HIP_MEMORY_SCOPE_AGENT);       // correctness mirror
      } else {
        __hip_atomic_store(&slot[jglob], pv, __ATOMIC_RELAXED,
                           __HIP_MEMORY_SCOPE_AGENT);       // round-6-proven
      }
      last[(size_t)b * HDIM + jglob] = hnew;     // off critical path
    }

    unsigned long long v;
    if constexpr (FAST != 0) {
      int it = 0;
      for (;;) {
        unsigned long long exp = 0xDEADBEEF00000000ull;     // tag 0xDEADBEEF impossible
        __hip_atomic_compare_exchange_strong(&slot[j], &exp, 0xDEADBEEF00000000ull,
            __ATOMIC_RELAXED, __ATOMIC_RELAXED, __HIP_MEMORY_SCOPE_WORKGROUP);
        v = exp;                                 // failed CAS returns current value
        if ((unsigned)(v >> 32) == (unsigned)b) break;
        if (++it >= (1 << 16)) {                 // L2 model wrong -> proven mirror
          int g2 = 0;
          do {
            v = __hip_atomic_load(&mslot[j], __ATOMIC_RELAXED,
                                  __HIP_MEMORY_SCOPE_AGENT);
          } while ((unsigned)(v >> 32) != (unsigned)b && ++g2 < (1 << 20));
          break;
        }
      }
    } else {
      int guard = 0;
      do {
        v = __hip_atomic_load(&slot[j], __ATOMIC_RELAXED,
                              __HIP_MEMORY_SCOPE_AGENT);
      } while ((unsigned)(v >> 32) != (unsigned)b && ++guard < (1 << 20));
    }

    union { unsigned u; float f; } hv; hv.u = (unsigned)v;
    hs[(b + 1) & 1][jphys] = hv.f;
    __syncthreads();                             // h(b+1) complete
  }
}

// Persistent recurrence: 16 workers (one XCD if round-robin), h-broadcast.
// WAR on parity buffer safe by induction (see r6). Both paths bit-identical.
__global__ void __launch_bounds__(512) gru_kernel(
    const float* __restrict__ W_hh, const float* __restrict__ b_hh,
    const float* __restrict__ xp, unsigned long long* __restrict__ hw,
    unsigned long long* __restrict__ mir, float* __restrict__ last,
    unsigned* __restrict__ cons)
{
  if (blockIdx.x & 7) return;                    // fillers exit
  const int nb   = blockIdx.x >> 3;              // 0..15
  const int tid  = threadIdx.x;
  const int lane = tid & 63;
  const int wave = tid >> 6;
  const int r4   = lane >> 4;
  const int c    = lane & 15;
  const int jj   = wave * 4 + r4;
  const int jglob = nb * JPB + jj;
  const bool prod = (c == 0);

  __shared__ float hs[2][16 * 36];
  __shared__ int fast_s;

  float4 wreg[3][8];
  float bias[3];
  #pragma unroll
  for (int g = 0; g < 3; ++g) {
    const float* wrow = W_hh + ((size_t)(g * HDIM + jglob)) * HDIM + c * 32;
    #pragma unroll
    for (int i = 0; i < 8; ++i) wreg[g][i] = ((const float4*)wrow)[i];
    bias[g] = b_hh[g * HDIM + jglob];
  }

  for (int w = tid; w < 16 * 36; w += 512) { hs[0][w] = 0.f; hs[1][w] = 0.f; }

  // XCD co-location consensus via proven AGENT atomics
  if (tid == 0) {
    unsigned xcc;
    asm volatile("s_getreg_b32 %0, hwreg(HW_REG_XCC_ID)" : "=s"(xcc));
    __hip_atomic_store(&cons[nb], 0x100u | (xcc & 0xFFu),
                       __ATOMIC_RELAXED, __HIP_MEMORY_SCOPE_AGENT);
    unsigned vals[NW];
    bool all; int it = 0;
    do {
      all = true;
      for (int i = 0; i < NW; ++i) {
        vals[i] = __hip_atomic_load(&cons[i], __ATOMIC_RELAXED,
                                    __HIP_MEMORY_SCOPE_AGENT);
        all = all && ((vals[i] >> 8) == 1u);
      }
      if (!all) __builtin_amdgcn_s_sleep(2);
    } while (!all && ++it < (1 << 20));
    bool eq = all;
    for (int i = 1; i < NW; ++i) eq = eq && (vals[i] == vals[0]);
    fast_s = eq ? 1 : 0;
  }
  __syncthreads();

  if (fast_s)
    run_steps<1>(tid, c, jglob, prod, wreg, bias, xp, hw, mir, last, hs);
  else
    run_steps<0>(tid, c, jglob, prod, wreg, bias, xp, hw, mir, last, hs);
}

// params[b,p] = dot(last[b,:], W_proj[p,:]) + b_proj[p]  (64x64 tiles, K=512)
__global__ void __launch_bounds__(256) proj_kernel(
    const float* __restrict__ last, const float* __restrict__ W_proj,
    const float* __restrict__ b_proj, float* __restrict__ params)
{
  const int tid = threadIdx.x;
  const int pt = blockIdx.x * 64;
  const int bt = blockIdx.y * 64;
  __shared__ float As[16 * 65];
  __shared__ float Bs[16 * 65];
  const int tb = (tid >> 4) * 4;
  const int tp = (tid & 15) * 4;
  float acc[4][4] = {};
  for (int k0 = 0; k0 < HDIM; k0 += 16) {
    #pragma unroll
    for (int i = 0; i < 4; ++i) {
      int idx = tid + i * 256;
      int k = idx & 15, m = idx >> 4;
      As[k * 65 + m] = last[(size_t)(bt + m) * HDIM + k0 + k];
      int gp = pt + m;
      Bs[k * 65 + m] = (gp < PDIM) ? W_proj[(size_t)gp * HDIM + k0 + k] : 0.f;
    }
    __syncthreads();
    #pragma unroll
    for (int k = 0; k < 16; ++k) {
      float a[4], bv[4];
      #pragma unroll
      for (int i = 0; i < 4; ++i) a[i] = As[k * 65 + tb + i];
      #pragma unroll
      for (int i = 0; i < 4; ++i) bv[i] = Bs[k * 65 + tp + i];
      #pragma unroll
      for (int i = 0; i < 4; ++i)
        #pragma unroll
        for (int jj = 0; jj < 4; ++jj) acc[i][jj] += a[i] * bv[jj];
    }
    __syncthreads();
  }
  #pragma unroll
  for (int i = 0; i < 4; ++i) {
    int gb = bt + tb + i;
    #pragma unroll
    for (int jj = 0; jj < 4; ++jj) {
      int gp = pt + tp + jj;
      if (gp < PDIM) params[(size_t)gb * PDIM + gp] = acc[i][jj] + b_proj[gp];
    }
  }
}

// samples[b,o] = sum_i w_i * (mu_i + (var_i+1e-6)*eps[i,b,o])
__global__ void mix_kernel(const float* __restrict__ params,
                           const float* __restrict__ eps,
                           float* __restrict__ out)
{
  int b = blockIdx.x, o = threadIdx.x;
  const float* pr = params + (size_t)b * PDIM;
  float s = 0.f;
  #pragma unroll
  for (int i = 0; i < G5; ++i) {
    float mu  = pr[i * ODIM + o];
    float var = pr[2 * i * ODIM + o] + 1e-6f;
    float w   = pr[2 * G5 * ODIM + i];
    float e   = eps[((size_t)i * BB + b) * ODIM + o];
    s += w * (mu + var * e);
  }
  out[(size_t)b * ODIM + o] = s;
}

extern "C" void kernel_launch(void* const* d_in, const int* in_sizes, int n_in,
                              void* d_out, int out_size, void* d_ws, size_t ws_size,
                              hipStream_t stream) {
  const float* ys     = (const float*)d_in[0];
  const float* W_ih   = (const float*)d_in[1];
  const float* W_hh   = (const float*)d_in[2];
  const float* b_ih   = (const float*)d_in[3];
  const float* b_hh   = (const float*)d_in[4];
  const float* W_proj = (const float*)d_in[5];
  const float* b_proj = (const float*)d_in[6];
  const float* eps    = (const float*)d_in[7];
  float* out = (float*)d_out;

  // workspace layout
  char* ws = (char*)d_ws;
  unsigned long long* hw  = (unsigned long long*)ws;          // 2*512*8 = 8 KB
  unsigned long long* mir = hw + 2 * HDIM;                    // 8 KB mirror
  unsigned* cons = (unsigned*)(ws + 4 * HDIM * 8);            // NW words
  float* xp     = (float*)(ws + 4 * HDIM * 8 + 256);          // 512*1536
  float* last   = xp + (size_t)BB * GDIM;                     // 512*512
  float* params = last + (size_t)BB * HDIM;                   // 512*1285

  hipMemsetAsync(hw, 0xFF, 4 * HDIM * 8, stream);             // hw + mir tags invalid
  hipMemsetAsync(cons, 0x00, 256, stream);

  dim3 gx(GDIM / 32, BB / 64);
  xp_kernel<<<gx, 512, 0, stream>>>(ys, W_ih, b_ih, xp);

  gru_kernel<<<NLAUNCH, 512, 0, stream>>>(W_hh, b_hh, xp, hw, mir, last, cons);

  dim3 gc((PDIM + 63) / 64, BB / 64);
  proj_kernel<<<gc, 256, 0, stream>>>(last, W_proj, b_proj, params);

  mix_kernel<<<BB, ODIM, 0, stream>>>(params, eps, out);
}

// Round 8
// 1023.161 us; speedup vs baseline: 1.8274x; 1.8274x over previous
//
#include <hip/hip_runtime.h>
#include <hip/hip_bf16.h>

#define IDIM 80
#define HDIM 512
#define ODIM 128
#define G5   5
#define BB   512
#define TT   512
#define PDIM 1285          // G*2*ODIM + G
#define GDIM 1536          // 3*HDIM
#define NB   48            // persistent blocks
#define RPB  32            // gh rows per block (1536/48)
#define PCPB 27            // proj cols per block (48*27=1296 >= 1285)

__device__ __forceinline__ void ag_storef(float* p, float v) {
  __hip_atomic_store(p, v, __ATOMIC_RELAXED, __HIP_MEMORY_SCOPE_AGENT);
}
__device__ __forceinline__ float ag_loadf(const float* p) {
  return __hip_atomic_load(p, __ATOMIC_RELAXED, __HIP_MEMORY_SCOPE_AGENT);
}
__device__ __forceinline__ void ag_storeu(unsigned long long* p, unsigned long long v) {
  __hip_atomic_store(p, v, __ATOMIC_RELAXED, __HIP_MEMORY_SCOPE_AGENT);
}
__device__ __forceinline__ unsigned long long ag_loadu(const unsigned long long* p) {
  return __hip_atomic_load(p, __ATOMIC_RELAXED, __HIP_MEMORY_SCOPE_AGENT);
}

// heavy barrier — used ONCE after phase 0 (round-1/2-proven)
__device__ __forceinline__ void grid_barrier(unsigned* bar, unsigned target) {
  __syncthreads();
  if (threadIdx.x == 0) {
    __hip_atomic_fetch_add(bar, 1u, __ATOMIC_ACQ_REL, __HIP_MEMORY_SCOPE_AGENT);
    while (__hip_atomic_load(bar, __ATOMIC_ACQUIRE, __HIP_MEMORY_SCOPE_AGENT) < target) {
      __builtin_amdgcn_s_sleep(1);
    }
  }
  __syncthreads();
}

// Round-2-proven structure: 48 blocks, gh exchange via tagged AGENT words,
// gates in consumer. Deltas vs r2: double-buffered h (ONE sync/step), and
// the projection GEMM fused into the poll-idle window (params[b-1,:] slice
// computed from LDS h while waiting for gh tags). proj_kernel removed.
__global__ void __launch_bounds__(512) gru_kernel(
    const float* __restrict__ ys, const float* __restrict__ W_ih,
    const float* __restrict__ W_hh, const float* __restrict__ b_ih,
    const float* __restrict__ b_hh, const float* __restrict__ W_proj,
    const float* __restrict__ b_proj,
    float* __restrict__ xp, unsigned long long* __restrict__ ghT,
    float* __restrict__ params, unsigned* __restrict__ bar)
{
  const int tid  = threadIdx.x;
  const int nb   = blockIdx.x;
  const int lane = tid & 63;
  const int wave = tid >> 6;
  const int r4   = lane >> 4;      // 0..3  row within wave
  const int c    = lane & 15;      // 0..15 column chunk (32 cols each)
  const int row  = nb * RPB + wave * 4 + r4;

  __shared__ float hs[2][16 * 36];   // h double-buffered, padded stride 36
  __shared__ float wih[32 * 82];     // W_ih rows for phase0
  __shared__ float bihs[32];

  // --- W_hh slice -> registers (32 weights/thread, r2 layout) ---
  float4 wreg[8];
  {
    const float4* wrow = (const float4*)(W_hh + (size_t)row * HDIM + c * 32);
    #pragma unroll
    for (int i = 0; i < 8; ++i) wreg[i] = wrow[i];
  }
  const float bhh_r = b_hh[row];

  // --- W_proj slice -> registers: 27 cols/block, 16 threads/col ---
  const int pcol = nb * PCPB + (tid >> 4);
  const int pcl  = tid & 15;
  const bool pact = (tid < 16 * PCPB) && (pcol < PDIM);
  float4 wp[8] = {};
  float bp = 0.f;
  if (pact) {
    const float4* wrow = (const float4*)(W_proj + (size_t)pcol * HDIM + pcl * 32);
    #pragma unroll
    for (int i = 0; i < 8; ++i) wp[i] = wrow[i];
    bp = b_proj[pcol];
  }

  for (int w = tid; w < 16 * 36; w += 512) { hs[0][w] = 0.f; hs[1][w] = 0.f; }

  // --- phase 0 (r2 exact): xp[:, block's 32 rows] = ys[:,T-1,:]@W_ih.T + b_ih
  for (int idx = tid; idx < 32 * IDIM; idx += 512) {
    int g = idx / IDIM, f = idx % IDIM;
    wih[g * 82 + f] = W_ih[(size_t)(nb * RPB + g) * IDIM + f];
  }
  if (tid < 32) bihs[tid] = b_ih[nb * RPB + tid];
  __syncthreads();
  {
    const int g = tid & 31, b0 = tid >> 5;
    for (int pass = 0; pass < 32; ++pass) {
      int b = pass * 16 + b0;
      const float* yrow = ys + ((size_t)b * TT + (TT - 1)) * IDIM;
      float acc = bihs[g];
      #pragma unroll
      for (int f = 0; f < IDIM; f += 2) {
        float2 wv = *(const float2*)(&wih[g * 82 + f]);
        float2 yv = *(const float2*)(&yrow[f]);
        acc += wv.x * yv.x + wv.y * yv.y;
      }
      ag_storef(&xp[(size_t)b * GDIM + nb * RPB + g], acc);
    }
  }
  grid_barrier(bar, NB * 1u);        // once: xp visible + tag memset valid

  const int j = tid;                 // h element this thread owns/consumes
  const int jphys = (j >> 5) * 36 + (j & 31);

  for (int b = 0; b < BB; ++b) {
    // xp prefetch (AGENT loads, r2-proven; latency hidden under matvec)
    const float* xpb = xp + (size_t)b * GDIM;
    float xr = ag_loadf(&xpb[j]);
    float xz = ag_loadf(&xpb[512 + j]);
    float xn = ag_loadf(&xpb[1024 + j]);

    // my gh row partial: 32 cols of W_hh[row,:] . h_b
    const float* hbase = &hs[b & 1][c * 36];
    float a0 = 0.f, a1 = 0.f, a2 = 0.f, a3 = 0.f;
    #pragma unroll
    for (int i = 0; i < 8; ++i) {
      float4 h4 = ((const float4*)hbase)[i];
      a0 += wreg[i].x * h4.x; a1 += wreg[i].y * h4.y;
      a2 += wreg[i].z * h4.z; a3 += wreg[i].w * h4.w;
    }
    float acc = (a0 + a1) + (a2 + a3);
    acc += __shfl_xor(acc, 1);
    acc += __shfl_xor(acc, 2);
    acc += __shfl_xor(acc, 4);
    acc += __shfl_xor(acc, 8);
    unsigned long long* ghb = ghT + (size_t)(b & 1) * GDIM;
    if (c == 0) {
      union { float f; unsigned u; } cv; cv.f = acc + bhh_r;
      unsigned long long pv = ((unsigned long long)(unsigned)b << 32) | cv.u;
      ag_storeu(&ghb[row], pv);
    }

    // ---- proj for row b-1, hidden in the poll-idle window ----
    // hs[b&1] == state after step b-1 == last[b-1]; reads are protected by
    // this iteration's end-sync (next write to hs[b&1] is in iter b+1).
    if (b >= 1 && pact) {
      const float* pb = &hs[b & 1][pcl * 36];
      float p0 = 0.f, p1 = 0.f, p2 = 0.f, p3 = 0.f;
      #pragma unroll
      for (int i = 0; i < 8; ++i) {
        float4 h4 = ((const float4*)pb)[i];
        p0 += wp[i].x * h4.x; p1 += wp[i].y * h4.y;
        p2 += wp[i].z * h4.z; p3 += wp[i].w * h4.w;
      }
      float pr = (p0 + p1) + (p2 + p3);
      pr += __shfl_xor(pr, 1);
      pr += __shfl_xor(pr, 2);
      pr += __shfl_xor(pr, 4);
      pr += __shfl_xor(pr, 8);
      if (pcl == 0) params[(size_t)(b - 1) * PDIM + pcol] = pr + bp;
    }

    // poll my 3 tagged gh words (r2-proven)
    float hr, hz, hn;
    {
      const unsigned long long* p0 = &ghb[j];
      const unsigned long long* p1 = &ghb[512 + j];
      const unsigned long long* p2 = &ghb[1024 + j];
      unsigned long long v0 = 0, v1 = 0, v2 = 0;
      bool d0 = false, d1 = false, d2 = false;
      int guard = 0;
      do {
        if (!d0) { v0 = ag_loadu(p0); d0 = ((unsigned)(v0 >> 32) == (unsigned)b); }
        if (!d1) { v1 = ag_loadu(p1); d1 = ((unsigned)(v1 >> 32) == (unsigned)b); }
        if (!d2) { v2 = ag_loadu(p2); d2 = ((unsigned)(v2 >> 32) == (unsigned)b); }
      } while ((!d0 || !d1 || !d2) && ++guard < (1 << 20));
      union { unsigned u; float f; } c0, c1, c2;
      c0.u = (unsigned)v0; c1.u = (unsigned)v1; c2.u = (unsigned)v2;
      hr = c0.f; hz = c1.f; hn = c2.f;
    }

    // gates in consumer (shortest producer chain, r2-proven)
    float h_old = hs[b & 1][jphys];
    float r = 1.f / (1.f + __expf(-(xr + hr)));
    float z = 1.f / (1.f + __expf(-(xz + hz)));
    float e2 = __expf(2.f * (xn + r * hn));
    float n = 1.f - 2.f / (e2 + 1.f);            // tanh, overflow-safe
    float hnew = (1.f - z) * n + z * h_old;
    hs[(b + 1) & 1][jphys] = hnew;               // other buffer: no WAR
    __syncthreads();                             // ONE sync per step
  }

  // epilogue: proj for row 511 from hs[512&1] = hs[0]
  if (pact) {
    const float* pb = &hs[0][pcl * 36];
    float p0 = 0.f, p1 = 0.f, p2 = 0.f, p3 = 0.f;
    #pragma unroll
    for (int i = 0; i < 8; ++i) {
      float4 h4 = ((const float4*)pb)[i];
      p0 += wp[i].x * h4.x; p1 += wp[i].y * h4.y;
      p2 += wp[i].z * h4.z; p3 += wp[i].w * h4.w;
    }
    float pr = (p0 + p1) + (p2 + p3);
    pr += __shfl_xor(pr, 1);
    pr += __shfl_xor(pr, 2);
    pr += __shfl_xor(pr, 4);
    pr += __shfl_xor(pr, 8);
    if (pcl == 0) params[(size_t)(BB - 1) * PDIM + pcol] = pr + bp;
  }
}

// samples[b,o] = sum_i w_i * (mu_i + (var_i+1e-6)*eps[i,b,o])
__global__ void mix_kernel(const float* __restrict__ params,
                           const float* __restrict__ eps,
                           float* __restrict__ out)
{
  int b = blockIdx.x, o = threadIdx.x;
  const float* pr = params + (size_t)b * PDIM;
  float s = 0.f;
  #pragma unroll
  for (int i = 0; i < G5; ++i) {
    float mu  = pr[i * ODIM + o];
    float var = pr[2 * i * ODIM + o] + 1e-6f;
    float w   = pr[2 * G5 * ODIM + i];
    float e   = eps[((size_t)i * BB + b) * ODIM + o];
    s += w * (mu + var * e);
  }
  out[(size_t)b * ODIM + o] = s;
}

extern "C" void kernel_launch(void* const* d_in, const int* in_sizes, int n_in,
                              void* d_out, int out_size, void* d_ws, size_t ws_size,
                              hipStream_t stream) {
  const float* ys     = (const float*)d_in[0];
  const float* W_ih   = (const float*)d_in[1];
  const float* W_hh   = (const float*)d_in[2];
  const float* b_ih   = (const float*)d_in[3];
  const float* b_hh   = (const float*)d_in[4];
  const float* W_proj = (const float*)d_in[5];
  const float* b_proj = (const float*)d_in[6];
  const float* eps    = (const float*)d_in[7];
  float* out = (float*)d_out;

  // workspace layout
  char* ws = (char*)d_ws;
  unsigned* bar           = (unsigned*)ws;                    // 256 B
  unsigned long long* ghT = (unsigned long long*)(ws + 256);  // 2*1536*8 = 24 KB
  float* xp     = (float*)(ws + 256 + 2 * GDIM * 8);          // 512*1536
  float* params = xp + (size_t)BB * GDIM;                     // 512*1285

  hipMemsetAsync(bar, 0, 256, stream);                 // barrier counter
  hipMemsetAsync(ghT, 0xFF, 2 * GDIM * 8, stream);     // tags invalid

  gru_kernel<<<NB, 512, 0, stream>>>(ys, W_ih, W_hh, b_ih, b_hh,
                                     W_proj, b_proj, xp, ghT, params, bar);

  mix_kernel<<<BB, ODIM, 0, stream>>>(params, eps, out);
}